// Round 1
// baseline (49.992 us; speedup 1.0000x reference)
//
#include <hip/hip_runtime.h>
#include <hip/hip_bf16.h>
#include <stdint.h>

typedef __attribute__((ext_vector_type(8))) short short8;
typedef __attribute__((ext_vector_type(4))) short short4v;
typedef __attribute__((ext_vector_type(4))) float f32x4;

#define N_ROWS 8192
#define DIM 256            // K
#define BM 128             // i-rows per block
#define BJ 128             // j-cols staged per LDS tile
#define JCHUNKS 8
#define JCHUNK (N_ROWS / JCHUNKS)   // 1024

// r' = r_normalized * sqrt(10 * log2(e)); then dot(r'_i,r'_j) = 10*log2(e)*sim,
// so exp(10*sim) = exp2(dot).  sqrt(10*1.4426950408889634) = 3.79828252...
#define SCL 3.79828252f

__device__ __forceinline__ unsigned short f2bf(float f) {
  uint32_t u = __builtin_bit_cast(uint32_t, f);
  u += 0x7fffu + ((u >> 16) & 1u);           // RTNE (no NaN/Inf here)
  return (unsigned short)(u >> 16);
}

// ---------------- Kernel A: normalize rows -> bf16 r', zero den & out -------
__global__ void k_norm(const float* __restrict__ reps,
                       unsigned short* __restrict__ rq,
                       float* __restrict__ den,
                       float* __restrict__ out) {
  const int w = threadIdx.x >> 6, lane = threadIdx.x & 63;
  const int row = blockIdx.x * 4 + w;
  const float4 v = reinterpret_cast<const float4*>(reps + row * DIM)[lane];
  float ss = v.x * v.x + v.y * v.y + v.z * v.z + v.w * v.w;
#pragma unroll
  for (int m = 1; m < 64; m <<= 1) ss += __shfl_xor(ss, m);
  const float scale = SCL / fmaxf(sqrtf(ss), 1e-12f);
  short4v o;
  o.x = (short)f2bf(v.x * scale);
  o.y = (short)f2bf(v.y * scale);
  o.z = (short)f2bf(v.z * scale);
  o.w = (short)f2bf(v.w * scale);
  *reinterpret_cast<short4v*>(rq + row * DIM + lane * 4) = o;
  if (threadIdx.x < 4) den[blockIdx.x * 4 + threadIdx.x] = 0.0f;
  if (blockIdx.x == 0 && threadIdx.x == 0) out[0] = 0.0f;
}

// ---------------- Kernel B: fused sim + exp + mask + row-sum ----------------
// grid (64, 8): blockIdx.x = i-tile (128 rows), blockIdx.y = j-chunk (1024 cols)
__global__ __launch_bounds__(256, 2) void k_sim(
    const unsigned short* __restrict__ rq,
    const int* __restrict__ lab,
    float* __restrict__ den) {
  __shared__ unsigned short Bs[BJ * DIM];  // 64 KB, 16B-chunk XOR-swizzled

  const int tid = threadIdx.x;
  const int w = tid >> 6, lane = tid & 63;
  const int l15 = lane & 15, lq = lane >> 4;
  const int ibase = blockIdx.x * BM + w * 32;   // this wave's 32 rows
  const int jc0 = blockIdx.y * JCHUNK;

  // A fragments in registers: 2 i-tiles x 8 k-chunks, 16B each
  short8 a[2][8];
#pragma unroll
  for (int t = 0; t < 2; ++t) {
    const unsigned short* ap = rq + (size_t)(ibase + t * 16 + l15) * DIM + lq * 8;
#pragma unroll
    for (int kc = 0; kc < 8; ++kc)
      a[t][kc] = *reinterpret_cast<const short8*>(ap + kc * 32);
  }
  // labels for the 8 output rows this lane owns (C/D: row=(lane>>4)*4+reg)
  int labi[2][4];
#pragma unroll
  for (int t = 0; t < 2; ++t)
#pragma unroll
    for (int r = 0; r < 4; ++r)
      labi[t][r] = lab[ibase + t * 16 + lq * 4 + r];

  f32x4 dsum[2] = {{0.f, 0.f, 0.f, 0.f}, {0.f, 0.f, 0.f, 0.f}};

  for (int jt = 0; jt < JCHUNK / BJ; ++jt) {
    const int j0 = jc0 + jt * BJ;
    __syncthreads();  // previous tile's reads done before overwrite
    // stage B tile: each wave stages 32 rows; LDS linear, global pre-swizzled
    {
      const int lrow0 = w * 32;
#pragma unroll
      for (int q = 0; q < 16; ++q) {
        const int lrow = lrow0 + q * 2 + (lane >> 5);
        const int ch = (lane & 31) ^ (lrow & 7);  // 16B-chunk swizzle
        const unsigned short* g = rq + (size_t)(j0 + lrow) * DIM + ch * 8;
        unsigned short* l = Bs + (lrow0 + q * 2) * DIM;  // +lane*16 implicit
        __builtin_amdgcn_global_load_lds(
            (const __attribute__((address_space(1))) uint32_t*)g,
            (__attribute__((address_space(3))) uint32_t*)l, 16, 0, 0);
      }
    }
    __syncthreads();  // drains vmcnt(0): staging complete

    // preload the 8 j-subtile labels for this tile
    int labj[8];
#pragma unroll
    for (int s = 0; s < 8; ++s) labj[s] = lab[j0 + s * 16 + l15];

#pragma unroll
    for (int s = 0; s < 8; ++s) {
      f32x4 acc0 = {0.f, 0.f, 0.f, 0.f};
      f32x4 acc1 = {0.f, 0.f, 0.f, 0.f};
      const int brow = s * 16 + l15;
      const unsigned short* bp = Bs + brow * DIM;
      const int sw = brow & 7;
#pragma unroll
      for (int kc = 0; kc < 8; ++kc) {
        const int c = (kc * 4 + lq) ^ sw;
        short8 b = *reinterpret_cast<const short8*>(bp + c * 8);
        acc0 = __builtin_amdgcn_mfma_f32_16x16x32_bf16(a[0][kc], b, acc0, 0, 0, 0);
        acc1 = __builtin_amdgcn_mfma_f32_16x16x32_bf16(a[1][kc], b, acc1, 0, 0, 0);
      }
#pragma unroll
      for (int r = 0; r < 4; ++r) {
        float e0 = __builtin_amdgcn_exp2f(acc0[r]);
        float e1 = __builtin_amdgcn_exp2f(acc1[r]);
        dsum[0][r] += (labi[0][r] == labj[s]) ? 1.0f : e0;
        dsum[1][r] += (labi[1][r] == labj[s]) ? 1.0f : e1;
      }
    }
  }

  // sum over the 16 lanes sharing each output row, then one atomic per row
#pragma unroll
  for (int t = 0; t < 2; ++t)
#pragma unroll
    for (int r = 0; r < 4; ++r) {
      float v = dsum[t][r];
      v += __shfl_xor(v, 1);
      v += __shfl_xor(v, 2);
      v += __shfl_xor(v, 4);
      v += __shfl_xor(v, 8);
      if (l15 == 0) atomicAdd(&den[ibase + t * 16 + lq * 4 + r], v);
    }
}

// ---------------- Kernel C: loss = mean(log(den + 1 + eps)) -----------------
__global__ void k_loss(const float* __restrict__ den, float* __restrict__ out) {
  const int idx = blockIdx.x * 256 + threadIdx.x;
  float v = logf(den[idx] + 1.0f + 1e-8f);  // +1 = num_diag
#pragma unroll
  for (int m = 1; m < 64; m <<= 1) v += __shfl_xor(v, m);
  __shared__ float sred[4];
  if ((threadIdx.x & 63) == 0) sred[threadIdx.x >> 6] = v;
  __syncthreads();
  if (threadIdx.x == 0)
    atomicAdd(out, (sred[0] + sred[1] + sred[2] + sred[3]) * (1.0f / (float)N_ROWS));
}

extern "C" void kernel_launch(void* const* d_in, const int* in_sizes, int n_in,
                              void* d_out, int out_size, void* d_ws, size_t ws_size,
                              hipStream_t stream) {
  const float* reps = (const float*)d_in[0];
  const int* lab = (const int*)d_in[1];
  float* out = (float*)d_out;
  unsigned short* rq = (unsigned short*)d_ws;                      // 4 MB bf16 r'
  float* den = (float*)((char*)d_ws + (size_t)N_ROWS * DIM * 2);   // 32 KB

  k_norm<<<N_ROWS / 4, 256, 0, stream>>>(reps, rq, den, out);
  k_sim<<<dim3(N_ROWS / BM, JCHUNKS), 256, 0, stream>>>(rq, lab, den);
  k_loss<<<N_ROWS / 256, 256, 0, stream>>>(den, out);
}